// Round 1
// baseline (46177.881 us; speedup 1.0000x reference)
//
#include <hip/hip_runtime.h>

// ScaledDotProductAttention: B=8,H=16,S=1024,D=64, fp32 in/out.
// Outputs concatenated: out [B,H,S,D] then attention [B,H,S,S].

constexpr int Bc = 8, Hc = 16, Sc = 1024, Dc = 64;
constexpr float NEGV = -1000000000.0f;
constexpr float SCALE = 0.125f;     // 1/sqrt(64)
constexpr int ROWS = 16;            // q-rows per block
constexpr int RPW = 4;              // q-rows per wave
constexpr int CH = 64;              // k-chunk
constexpr int NCH = Sc / CH;        // 16

__global__ __launch_bounds__(256, 2) void attn_fused(
    const float* __restrict__ Q, const float* __restrict__ K,
    const float* __restrict__ V, const int* __restrict__ M,
    float* __restrict__ Out, float* __restrict__ Attn)
{
    __shared__ float qs[ROWS][Dc];        // 4 KB
    __shared__ float kbuf[CH * Dc];       // 16 KB, XOR-swizzled
    __shared__ float psm[ROWS][CH];       // 4 KB

    const int t = threadIdx.x;
    const int lane = t & 63;
    const int w = t >> 6;
    const int bh = blockIdx.y;            // 0..127
    const int b = bh >> 4;                // H=16
    const int qtile = blockIdx.x * ROWS;
    const int wq = qtile + w * RPW;       // wave's first q-row

    const float* Qb = Q + (size_t)bh * Sc * Dc;
    const float* Kb = K + (size_t)bh * Sc * Dc;
    const float* Vb = V + (size_t)bh * Sc * Dc;
    const int*   Mb = M + (size_t)b * Sc * Sc;

    // stage Q rows (read later through the j-loop's first barrier)
    for (int i = t; i < ROWS * Dc; i += 256) {
        qs[i >> 6][i & 63] = Qb[(size_t)(qtile + (i >> 6)) * Dc + (i & 63)];
    }

    // mask bits: vb[r] bit j = valid(mask[b][wq+r][j*64+lane])
    unsigned vb[RPW];
#pragma unroll
    for (int r = 0; r < RPW; ++r) {
        unsigned m = 0;
#pragma unroll
        for (int j = 0; j < NCH; ++j) {
            m |= (Mb[(size_t)(wq + r) * Sc + j * CH + lane] != 0 ? 1u : 0u) << j;
        }
        vb[r] = m;
    }

    const int lsw = lane & 15;
    float s[RPW][NCH];

    // ---- scores: s[r][j] = (Q[wq+r] . K[j*64+lane]) * SCALE, masked ----
#pragma unroll
    for (int j = 0; j < NCH; ++j) {
        __syncthreads();   // protect kbuf reuse (and qs on first iter)
        for (int i = t; i < CH * Dc; i += 256) {
            const int k = i >> 6, d = i & 63;
            kbuf[(k << 6) + ((((d >> 2) ^ (k & 15)) << 2) | (d & 3))] =
                Kb[(size_t)(j * CH + k) * Dc + d];
        }
        __syncthreads();
        float a0 = 0.f, a1 = 0.f, a2 = 0.f, a3 = 0.f;
#pragma unroll
        for (int d4 = 0; d4 < 16; ++d4) {
            const float4 kv = *(const float4*)&kbuf[(lane << 6) + ((d4 ^ lsw) << 2)];
            const float4 q0 = *(const float4*)&qs[w * RPW + 0][d4 << 2];
            const float4 q1 = *(const float4*)&qs[w * RPW + 1][d4 << 2];
            const float4 q2 = *(const float4*)&qs[w * RPW + 2][d4 << 2];
            const float4 q3 = *(const float4*)&qs[w * RPW + 3][d4 << 2];
            a0 += kv.x * q0.x + kv.y * q0.y + kv.z * q0.z + kv.w * q0.w;
            a1 += kv.x * q1.x + kv.y * q1.y + kv.z * q1.z + kv.w * q1.w;
            a2 += kv.x * q2.x + kv.y * q2.y + kv.z * q2.z + kv.w * q2.w;
            a3 += kv.x * q3.x + kv.y * q3.y + kv.z * q3.z + kv.w * q3.w;
        }
        s[0][j] = (vb[0] >> j & 1) ? a0 * SCALE : NEGV;
        s[1][j] = (vb[1] >> j & 1) ? a1 * SCALE : NEGV;
        s[2][j] = (vb[2] >> j & 1) ? a2 * SCALE : NEGV;
        s[3][j] = (vb[3] >> j & 1) ? a3 * SCALE : NEGV;
    }

    // ---- softmax (per row, wave-wide reduce) + attention write ----
#pragma unroll
    for (int r = 0; r < RPW; ++r) {
        float mx = -3.4e38f;
#pragma unroll
        for (int j = 0; j < NCH; ++j) mx = fmaxf(mx, s[r][j]);
        for (int off = 32; off; off >>= 1) mx = fmaxf(mx, __shfl_xor(mx, off, 64));
        float sum = 0.f;
#pragma unroll
        for (int j = 0; j < NCH; ++j) {
            const float p = __expf(s[r][j] - mx);
            s[r][j] = p;
            sum += p;
        }
        for (int off = 32; off; off >>= 1) sum += __shfl_xor(sum, off, 64);
        const float inv = 1.0f / sum;
        float* arow = Attn + (size_t)bh * Sc * Sc + (size_t)(wq + r) * Sc;
#pragma unroll
        for (int j = 0; j < NCH; ++j) {
            const float a = (vb[r] >> j & 1) ? s[r][j] * inv : 0.0f;
            s[r][j] = a;
            arow[j * CH + lane] = a;
        }
    }

    // ---- PV: out[wq+r][lane] = sum_k attn[r][k] * V[k][lane] ----
    float o0 = 0.f, o1 = 0.f, o2 = 0.f, o3 = 0.f;
    const int l4 = lane >> 2, lm = lane & 3;
#pragma unroll
    for (int j = 0; j < NCH; ++j) {
        __syncthreads();   // protect kbuf/psm reuse
        for (int i = t; i < CH * Dc; i += 256) {
            const int k = i >> 6, d = i & 63;
            kbuf[(k << 6) + ((((d >> 2) ^ (k & 15)) << 2) | (d & 3))] =
                Vb[(size_t)(j * CH + k) * Dc + d];
        }
        psm[w * RPW + 0][lane] = s[0][j];
        psm[w * RPW + 1][lane] = s[1][j];
        psm[w * RPW + 2][lane] = s[2][j];
        psm[w * RPW + 3][lane] = s[3][j];
        __syncthreads();
#pragma unroll
        for (int k4 = 0; k4 < 16; ++k4) {
            const float4 p0 = *(const float4*)&psm[w * RPW + 0][k4 << 2];
            const float4 p1 = *(const float4*)&psm[w * RPW + 1][k4 << 2];
            const float4 p2 = *(const float4*)&psm[w * RPW + 2][k4 << 2];
            const float4 p3 = *(const float4*)&psm[w * RPW + 3][k4 << 2];
            const int k0 = k4 << 2;
            const float v0 = kbuf[((k0 + 0) << 6) + (((l4 ^ ((k0 + 0) & 15)) << 2) | lm)];
            const float v1 = kbuf[((k0 + 1) << 6) + (((l4 ^ ((k0 + 1) & 15)) << 2) | lm)];
            const float v2 = kbuf[((k0 + 2) << 6) + (((l4 ^ ((k0 + 2) & 15)) << 2) | lm)];
            const float v3 = kbuf[((k0 + 3) << 6) + (((l4 ^ ((k0 + 3) & 15)) << 2) | lm)];
            o0 += p0.x * v0 + p0.y * v1 + p0.z * v2 + p0.w * v3;
            o1 += p1.x * v0 + p1.y * v1 + p1.z * v2 + p1.w * v3;
            o2 += p2.x * v0 + p2.y * v1 + p2.z * v2 + p2.w * v3;
            o3 += p3.x * v0 + p3.y * v1 + p3.z * v2 + p3.w * v3;
        }
    }
    Out[(size_t)(bh * Sc + wq + 0) * Dc + lane] = o0;
    Out[(size_t)(bh * Sc + wq + 1) * Dc + lane] = o1;
    Out[(size_t)(bh * Sc + wq + 2) * Dc + lane] = o2;
    Out[(size_t)(bh * Sc + wq + 3) * Dc + lane] = o3;
}

extern "C" void kernel_launch(void* const* d_in, const int* in_sizes, int n_in,
                              void* d_out, int out_size, void* d_ws, size_t ws_size,
                              hipStream_t stream) {
    const float* Q = (const float*)d_in[0];
    const float* K = (const float*)d_in[1];
    const float* V = (const float*)d_in[2];
    const int*   M = (const int*)d_in[3];

    float* Out  = (float*)d_out;                                   // B*H*S*D
    float* Attn = (float*)d_out + (size_t)Bc * Hc * Sc * Dc;       // B*H*S*S

    dim3 grid(Sc / ROWS, Bc * Hc);
    dim3 block(256);
    attn_fused<<<grid, block, 0, stream>>>(Q, K, V, M, Out, Attn);
}

// Round 2
// 597.515 us; speedup vs baseline: 77.2832x; 77.2832x over previous
//
#include <hip/hip_runtime.h>

// B=8,H=16,S=1024,D=64 fp32 attention with full attention-matrix output.
// Outputs: out [B,H,S,D] then attention [B,H,S,S], concatenated fp32.

typedef _Float16 half8 __attribute__((ext_vector_type(8)));
typedef float floatx4 __attribute__((ext_vector_type(4)));

constexpr int Bc = 8, Hc = 16, Sc = 1024, Dc = 64;
constexpr float NEGV = -1000000000.0f;
constexpr float SCALE = 0.125f;   // 1/sqrt(64)
constexpr int PROW = 1032;        // p_lds row pitch in fp16 (1024 + 8 pad -> 2-way-free banks)

__device__ inline half8 cvt8(float4 a, float4 b) {
    half8 h;
    h[0] = (_Float16)a.x; h[1] = (_Float16)a.y; h[2] = (_Float16)a.z; h[3] = (_Float16)a.w;
    h[4] = (_Float16)b.x; h[5] = (_Float16)b.y; h[6] = (_Float16)b.z; h[7] = (_Float16)b.w;
    return h;
}

__global__ __launch_bounds__(256) void attn_mfma(
    const float* __restrict__ Q, const float* __restrict__ K,
    const float* __restrict__ V, const int* __restrict__ M,
    float* __restrict__ Out, float* __restrict__ Attn)
{
    __shared__ _Float16 p_lds[16][PROW];   // 33 KB: P in fp16, padded
    __shared__ float redM[4][16];
    __shared__ float redS[4][16];

    const int t = threadIdx.x;
    const int lane = t & 63;
    const int w = t >> 6;            // wave 0..3
    const int g = lane >> 4;         // 0..3
    const int n = lane & 15;
    const int bh = blockIdx.y;
    const int b = bh >> 4;
    const int qtile = blockIdx.x * 16;
    const int kbase = w * 256;       // this wave's key slice for phase 1

    const float* Qb = Q + (size_t)bh * Sc * Dc;
    const float* Kb = K + (size_t)bh * Sc * Dc;
    const float* Vb = V + (size_t)bh * Sc * Dc;
    const int*   Mb = M + (size_t)b * Sc * Sc;

    // ---- Q A-fragments, straight from global (row = n, k-contiguous) ----
    half8 qf0, qf1;
    {
        const float* qr = Qb + (size_t)(qtile + n) * Dc;
        const float4 a0 = *(const float4*)&qr[g * 8];
        const float4 a1 = *(const float4*)&qr[g * 8 + 4];
        const float4 a2 = *(const float4*)&qr[32 + g * 8];
        const float4 a3 = *(const float4*)&qr[32 + g * 8 + 4];
        qf0 = cvt8(a0, a1);
        qf1 = cvt8(a2, a3);
    }

    // ---- Phase 1: scores for 16 q-rows x this wave's 256 keys ----
    const int qrow = qtile + g * 4;          // D-layout rows qrow..qrow+3
    float s[64];                             // statically indexed only
#pragma unroll
    for (int kt = 0; kt < 16; ++kt) {
        const int key = kbase + kt * 16 + n;
        const float* kr = Kb + (size_t)key * Dc;
        const float4 b0 = *(const float4*)&kr[g * 8];
        const float4 b1 = *(const float4*)&kr[g * 8 + 4];
        const float4 b2 = *(const float4*)&kr[32 + g * 8];
        const float4 b3 = *(const float4*)&kr[32 + g * 8 + 4];
        floatx4 acc = {0.f, 0.f, 0.f, 0.f};
        acc = __builtin_amdgcn_mfma_f32_16x16x32_f16(qf0, cvt8(b0, b1), acc, 0, 0, 0);
        acc = __builtin_amdgcn_mfma_f32_16x16x32_f16(qf1, cvt8(b2, b3), acc, 0, 0, 0);
#pragma unroll
        for (int r = 0; r < 4; ++r) {
            const int mv = Mb[(size_t)(qrow + r) * Sc + key];
            s[kt * 4 + r] = mv ? acc[r] * SCALE : NEGV;
        }
    }

    // ---- Softmax: row max (wave-partial -> block), exp, sum, normalize ----
    float mx[4];
#pragma unroll
    for (int r = 0; r < 4; ++r) {
        float m = s[r];
#pragma unroll
        for (int kt = 1; kt < 16; ++kt) m = fmaxf(m, s[kt * 4 + r]);
        m = fmaxf(m, __shfl_xor(m, 1, 64));
        m = fmaxf(m, __shfl_xor(m, 2, 64));
        m = fmaxf(m, __shfl_xor(m, 4, 64));
        m = fmaxf(m, __shfl_xor(m, 8, 64));
        mx[r] = m;
    }
    if (n == 0) {
#pragma unroll
        for (int r = 0; r < 4; ++r) redM[w][g * 4 + r] = mx[r];
    }
    __syncthreads();
#pragma unroll
    for (int r = 0; r < 4; ++r) {
        mx[r] = fmaxf(fmaxf(redM[0][g * 4 + r], redM[1][g * 4 + r]),
                      fmaxf(redM[2][g * 4 + r], redM[3][g * 4 + r]));
    }
    float sum[4] = {0.f, 0.f, 0.f, 0.f};
#pragma unroll
    for (int kt = 0; kt < 16; ++kt) {
#pragma unroll
        for (int r = 0; r < 4; ++r) {
            const float p = __expf(s[kt * 4 + r] - mx[r]);
            s[kt * 4 + r] = p;
            sum[r] += p;
        }
    }
#pragma unroll
    for (int r = 0; r < 4; ++r) {
        float z = sum[r];
        z += __shfl_xor(z, 1, 64);
        z += __shfl_xor(z, 2, 64);
        z += __shfl_xor(z, 4, 64);
        z += __shfl_xor(z, 8, 64);
        sum[r] = z;
    }
    if (n == 0) {
#pragma unroll
        for (int r = 0; r < 4; ++r) redS[w][g * 4 + r] = sum[r];
    }
    __syncthreads();
    float inv[4];
#pragma unroll
    for (int r = 0; r < 4; ++r) {
        inv[r] = 1.0f / (redS[0][g * 4 + r] + redS[1][g * 4 + r] +
                         redS[2][g * 4 + r] + redS[3][g * 4 + r]);
    }

    // ---- Attention write (coalesced) + P -> LDS fp16 (A-layout source) ----
    float* Ab = Attn + (size_t)bh * Sc * Sc;
#pragma unroll
    for (int kt = 0; kt < 16; ++kt) {
        const int col = kbase + kt * 16 + n;
#pragma unroll
        for (int r = 0; r < 4; ++r) {
            const float p = s[kt * 4 + r] * inv[r];   // masked -> exp underflow -> exact 0
            Ab[(size_t)(qrow + r) * Sc + col] = p;
            p_lds[g * 4 + r][col] = (_Float16)p;
        }
    }
    __syncthreads();

    // ---- Phase 2: PV. Wave owns d-slice [w*16, w*16+16); full k=1024 ----
    const int dcol = w * 16 + n;
    floatx4 oacc = {0.f, 0.f, 0.f, 0.f};
#pragma unroll 4
    for (int i = 0; i < 32; ++i) {
        const half8 pa = *(const half8*)&p_lds[n][i * 32 + g * 8];
        half8 vb8;
#pragma unroll
        for (int j = 0; j < 8; ++j) {
            vb8[j] = (_Float16)Vb[(size_t)(i * 32 + g * 8 + j) * Dc + dcol];
        }
        oacc = __builtin_amdgcn_mfma_f32_16x16x32_f16(pa, vb8, oacc, 0, 0, 0);
    }
    float* Ob = Out + (size_t)bh * Sc * Dc;
#pragma unroll
    for (int r = 0; r < 4; ++r) {
        Ob[(size_t)(qrow + r) * Dc + dcol] = oacc[r];
    }
}

extern "C" void kernel_launch(void* const* d_in, const int* in_sizes, int n_in,
                              void* d_out, int out_size, void* d_ws, size_t ws_size,
                              hipStream_t stream) {
    const float* Q = (const float*)d_in[0];
    const float* K = (const float*)d_in[1];
    const float* V = (const float*)d_in[2];
    const int*   M = (const int*)d_in[3];

    float* Out  = (float*)d_out;
    float* Attn = (float*)d_out + (size_t)Bc * Hc * Sc * Dc;

    dim3 grid(Sc / 16, Bc * Hc);
    dim3 block(256);
    attn_mfma<<<grid, block, 0, stream>>>(Q, K, V, M, Out, Attn);
}

// Round 3
// 456.866 us; speedup vs baseline: 101.0754x; 1.3079x over previous
//
#include <hip/hip_runtime.h>

// B=8,H=16,S=1024,D=64 fp32 attention with full attention-matrix output.
// Outputs: out [B,H,S,D] then attention [B,H,S,S], concatenated fp32.

typedef _Float16 half4 __attribute__((ext_vector_type(4)));
typedef _Float16 half8 __attribute__((ext_vector_type(8)));
typedef float floatx4 __attribute__((ext_vector_type(4)));

constexpr int Bc = 8, Hc = 16, Sc = 1024, Dc = 64;
constexpr float NEGV = -1000000000.0f;
constexpr float SCALE = 0.125f;   // 1/sqrt(64)
constexpr int PROW = 1032;        // p_lds pitch (fp16): 2064 B -> word-stride 516 == 4 mod 32

__device__ inline half8 cvt8(float4 a, float4 b) {
    half8 h;
    h[0] = (_Float16)a.x; h[1] = (_Float16)a.y; h[2] = (_Float16)a.z; h[3] = (_Float16)a.w;
    h[4] = (_Float16)b.x; h[5] = (_Float16)b.y; h[6] = (_Float16)b.z; h[7] = (_Float16)b.w;
    return h;
}

__global__ __launch_bounds__(256) void attn_mfma3(
    const float* __restrict__ Q, const float* __restrict__ K,
    const float* __restrict__ V, const int* __restrict__ M,
    float* __restrict__ Out, float* __restrict__ Attn)
{
    __shared__ _Float16 p_lds[16][PROW];   // 33 KB
    __shared__ _Float16 Vt[8192];          // 16 KB: V chunk, tr-read subtiled
    __shared__ float redM[4][16];
    __shared__ float redS[4][16];

    const int t = threadIdx.x;
    const int lane = t & 63;
    const int w = t >> 6;            // wave 0..3
    const int g = lane >> 4;         // 0..3
    const int n = lane & 15;
    const int bh = blockIdx.y;
    const int b = bh >> 4;
    const int qtile = blockIdx.x * 16;
    const int kbase = w * 256;       // wave's key slice for phase 1

    const float* Qb = Q + (size_t)bh * Sc * Dc;
    const float* Kb = K + (size_t)bh * Sc * Dc;
    const float* Vb = V + (size_t)bh * Sc * Dc;
    const int*   Mb = M + (size_t)b * Sc * Sc;

    // ---- Q A-fragments direct from global (row = n, d-contiguous) ----
    half8 qf0, qf1;
    {
        const float* qr = Qb + (size_t)(qtile + n) * Dc;
        const float4 a0 = *(const float4*)&qr[g * 8];
        const float4 a1 = *(const float4*)&qr[g * 8 + 4];
        const float4 a2 = *(const float4*)&qr[32 + g * 8];
        const float4 a3 = *(const float4*)&qr[32 + g * 8 + 4];
        qf0 = cvt8(a0, a1);
        qf1 = cvt8(a2, a3);
    }

    // ---- Phase 1: scores for 16 q-rows x wave's 256 keys ----
    const int qrow = qtile + g * 4;
    float s[64];                      // statically indexed only
#pragma unroll
    for (int kt = 0; kt < 16; ++kt) {
        const int key = kbase + kt * 16 + n;
        const float* kr = Kb + (size_t)key * Dc;
        const float4 b0 = *(const float4*)&kr[g * 8];
        const float4 b1 = *(const float4*)&kr[g * 8 + 4];
        const float4 b2 = *(const float4*)&kr[32 + g * 8];
        const float4 b3 = *(const float4*)&kr[32 + g * 8 + 4];
        floatx4 acc = {0.f, 0.f, 0.f, 0.f};
        acc = __builtin_amdgcn_mfma_f32_16x16x32_f16(qf0, cvt8(b0, b1), acc, 0, 0, 0);
        acc = __builtin_amdgcn_mfma_f32_16x16x32_f16(qf1, cvt8(b2, b3), acc, 0, 0, 0);
#pragma unroll
        for (int r = 0; r < 4; ++r) {
            const int mv = Mb[(size_t)(qrow + r) * Sc + key];
            s[kt * 4 + r] = mv ? acc[r] * SCALE : NEGV;
        }
    }

    // ---- Softmax ----
    float mx[4];
#pragma unroll
    for (int r = 0; r < 4; ++r) {
        float m = s[r];
#pragma unroll
        for (int kt = 1; kt < 16; ++kt) m = fmaxf(m, s[kt * 4 + r]);
        m = fmaxf(m, __shfl_xor(m, 1, 64));
        m = fmaxf(m, __shfl_xor(m, 2, 64));
        m = fmaxf(m, __shfl_xor(m, 4, 64));
        m = fmaxf(m, __shfl_xor(m, 8, 64));
        mx[r] = m;
    }
    if (n == 0) {
#pragma unroll
        for (int r = 0; r < 4; ++r) redM[w][g * 4 + r] = mx[r];
    }
    __syncthreads();
#pragma unroll
    for (int r = 0; r < 4; ++r) {
        mx[r] = fmaxf(fmaxf(redM[0][g * 4 + r], redM[1][g * 4 + r]),
                      fmaxf(redM[2][g * 4 + r], redM[3][g * 4 + r]));
    }
    float sum[4] = {0.f, 0.f, 0.f, 0.f};
#pragma unroll
    for (int kt = 0; kt < 16; ++kt) {
#pragma unroll
        for (int r = 0; r < 4; ++r) {
            const float p = __expf(s[kt * 4 + r] - mx[r]);
            s[kt * 4 + r] = p;
            sum[r] += p;
        }
    }
#pragma unroll
    for (int r = 0; r < 4; ++r) {
        float z = sum[r];
        z += __shfl_xor(z, 1, 64);
        z += __shfl_xor(z, 2, 64);
        z += __shfl_xor(z, 4, 64);
        z += __shfl_xor(z, 8, 64);
        sum[r] = z;
    }
    if (n == 0) {
#pragma unroll
        for (int r = 0; r < 4; ++r) redS[w][g * 4 + r] = sum[r];
    }
    __syncthreads();
    float inv[4];
#pragma unroll
    for (int r = 0; r < 4; ++r) {
        inv[r] = 1.0f / (redS[0][g * 4 + r] + redS[1][g * 4 + r] +
                         redS[2][g * 4 + r] + redS[3][g * 4 + r]);
    }

    // ---- P (normalized) -> p_lds fp16; masked entries are exp-underflow 0 ----
#pragma unroll
    for (int kt = 0; kt < 16; ++kt) {
        const int col = kbase + kt * 16 + n;
#pragma unroll
        for (int r = 0; r < 4; ++r) {
            p_lds[g * 4 + r][col] = (_Float16)(s[kt * 4 + r] * inv[r]);
        }
    }
    __syncthreads();

    // ---- Prologue: V chunk 0 -> regs (in flight during Attn store) ----
    const int klb = t >> 4;           // k_local = it*16 + klb
    const int dst = (t & 15) * 4;     // d = dst..dst+3
    float4 vreg[8];
#pragma unroll
    for (int it = 0; it < 8; ++it) {
        vreg[it] = *(const float4*)&Vb[(size_t)(it * 16 + klb) * Dc + dst];
    }

    // ---- Attn store, coalesced float4 from p_lds ----
    {
        const int row = t >> 4;
        float* arow = Attn + (size_t)bh * Sc * Sc + (size_t)(qtile + row) * Sc;
#pragma unroll
        for (int cc = 0; cc < 16; ++cc) {
            const int col = cc * 64 + (t & 15) * 4;
            const half4 h = *(const half4*)&p_lds[row][col];
            float4 f;
            f.x = (float)h[0]; f.y = (float)h[1]; f.z = (float)h[2]; f.w = (float)h[3];
            *(float4*)&arow[col] = f;
        }
    }

    // ---- Phase 2: O = P @ V via LDS-staged V + ds_read_b64_tr_b16 ----
    // Vt layout (fp16 units): ((kb*4 + d0)*8 + sub*4 + g)*64 + j*16 + dd
    // where tile(kb,d0,sub,g)[j][dd] = V[c*128 + kb*32 + g*8 + sub*4 + j][d0*16 + dd]
    floatx4 oacc = {0.f, 0.f, 0.f, 0.f};
    const unsigned vt_base = (unsigned)(uintptr_t)&Vt[0];
    const unsigned d0w = (unsigned)w;

    for (int c = 0; c < 8; ++c) {
        __syncthreads();   // prev chunk's tr_reads complete (lgkmcnt(0) before MFMA)
#pragma unroll
        for (int it = 0; it < 8; ++it) {
            const int k_l = it * 16 + klb;
            const int off = (((k_l >> 5) * 4 + (dst >> 4)) * 8 +
                             ((k_l >> 2) & 1) * 4 + ((k_l >> 3) & 3)) * 64 +
                            (k_l & 3) * 16 + (dst & 15);
            half4 h;
            h[0] = (_Float16)vreg[it].x; h[1] = (_Float16)vreg[it].y;
            h[2] = (_Float16)vreg[it].z; h[3] = (_Float16)vreg[it].w;
            *(half4*)&Vt[off] = h;
        }
        __syncthreads();
        if (c < 7) {
#pragma unroll
            for (int it = 0; it < 8; ++it) {
                vreg[it] = *(const float4*)&Vb[(size_t)((c + 1) * 128 + it * 16 + klb) * Dc + dst];
            }
        }
#pragma unroll
        for (int kb = 0; kb < 4; ++kb) {
            const half8 pa = *(const half8*)&p_lds[n][c * 128 + kb * 32 + g * 8];
            const unsigned vaddr = vt_base +
                (((unsigned)kb * 4 + d0w) * 8 + (unsigned)g) * 128 + (unsigned)n * 8;
            half4 r0, r1;
            asm volatile("ds_read_b64_tr_b16 %0, %2\n\t"
                         "ds_read_b64_tr_b16 %1, %2 offset:512"
                         : "=&v"(r0), "=&v"(r1) : "v"(vaddr));
            asm volatile("s_waitcnt lgkmcnt(0)" ::: "memory");
            __builtin_amdgcn_sched_barrier(0);
            half8 vb8;
            vb8[0] = r0[0]; vb8[1] = r0[1]; vb8[2] = r0[2]; vb8[3] = r0[3];
            vb8[4] = r1[0]; vb8[5] = r1[1]; vb8[6] = r1[2]; vb8[7] = r1[3];
            oacc = __builtin_amdgcn_mfma_f32_16x16x32_f16(pa, vb8, oacc, 0, 0, 0);
        }
    }

    const int dcol = w * 16 + n;
    float* Ob = Out + (size_t)bh * Sc * Dc;
#pragma unroll
    for (int r = 0; r < 4; ++r) {
        Ob[(size_t)(qrow + r) * Dc + dcol] = oacc[r];
    }
}

extern "C" void kernel_launch(void* const* d_in, const int* in_sizes, int n_in,
                              void* d_out, int out_size, void* d_ws, size_t ws_size,
                              hipStream_t stream) {
    const float* Q = (const float*)d_in[0];
    const float* K = (const float*)d_in[1];
    const float* V = (const float*)d_in[2];
    const int*   M = (const int*)d_in[3];

    float* Out  = (float*)d_out;
    float* Attn = (float*)d_out + (size_t)Bc * Hc * Sc * Dc;

    dim3 grid(Sc / 16, Bc * Hc);
    dim3 block(256);
    attn_mfma3<<<grid, block, 0, stream>>>(Q, K, V, M, Out, Attn);
}

// Round 4
// 342.027 us; speedup vs baseline: 135.0124x; 1.3358x over previous
//
#include <hip/hip_runtime.h>
#include <stdint.h>

// B=8,H=16,S=1024,D=64 fp32 attention with full attention-matrix output.
// Outputs: out [B,H,S,D] then attention [B,H,S,S], concatenated fp32.

typedef _Float16 half8 __attribute__((ext_vector_type(8)));
typedef _Float16 half4v __attribute__((ext_vector_type(4)));
typedef float floatx4 __attribute__((ext_vector_type(4)));
typedef unsigned short u16;
typedef u16 u16x4 __attribute__((ext_vector_type(4)));

constexpr int Bc = 8, Hc = 16, Sc = 1024, Dc = 64;
constexpr float NEGV = -1000000000.0f;
constexpr float SCALE = 0.125f;   // 1/sqrt(64)

__device__ inline half8 cvt8(float4 a, float4 b) {
    half8 h;
    h[0] = (_Float16)a.x; h[1] = (_Float16)a.y; h[2] = (_Float16)a.z; h[3] = (_Float16)a.w;
    h[4] = (_Float16)b.x; h[5] = (_Float16)b.y; h[6] = (_Float16)b.z; h[7] = (_Float16)b.w;
    return h;
}

// ---- pre-kernel 1: K,V fp32 -> fp16 ----
__global__ __launch_bounds__(256) void cvt_f16_kernel(
    const float* __restrict__ K, const float* __restrict__ V,
    _Float16* __restrict__ Kh, _Float16* __restrict__ Vh)
{
    const size_t nv = (size_t)Bc * Hc * Sc * Dc / 4;   // float4 count per tensor
    for (size_t i = (size_t)blockIdx.x * blockDim.x + threadIdx.x; i < 2 * nv;
         i += (size_t)gridDim.x * blockDim.x) {
        const bool isK = i < nv;
        const size_t j = isK ? i : i - nv;
        const float4 f = ((const float4*)(isK ? K : V))[j];
        half4v h;
        h[0] = (_Float16)f.x; h[1] = (_Float16)f.y;
        h[2] = (_Float16)f.z; h[3] = (_Float16)f.w;
        *(half4v*)((isK ? Kh : Vh) + j * 4) = h;
    }
}

// ---- pre-kernel 2: mask int32 -> bit-packed u16 per column per 16-row tile ----
__global__ __launch_bounds__(256) void pack_mask_kernel(
    const int* __restrict__ M, u16* __restrict__ MB)
{
    const int id = blockIdx.x;                 // 2048 = 8b * 64qt * 4cg
    const int cg = id & 3, qt = (id >> 2) & 63, b = id >> 8;
    const int col = cg * 256 + threadIdx.x;
    const int* base = M + ((size_t)b * Sc + qt * 16) * Sc + col;
    unsigned m = 0;
#pragma unroll
    for (int r = 0; r < 16; ++r) m |= (base[(size_t)r * Sc] != 0 ? 1u : 0u) << r;
    MB[(size_t)(b * 64 + qt) * 1024 + col] = (u16)m;
}

template<bool PRE>
__global__ __launch_bounds__(256, 4) void attn4(
    const float* __restrict__ Q, const float* __restrict__ K,
    const float* __restrict__ V, const int* __restrict__ M,
    const _Float16* __restrict__ Kh, const _Float16* __restrict__ Vh,
    const u16* __restrict__ MB,
    float* __restrict__ Out, float* __restrict__ Attn)
{
    // 40 KB total -> 4 blocks/CU. Vt aliases mb2 (mask bits dead before phase 2).
    __shared__ __align__(16) unsigned char sh[40960];
    _Float16* p_lds = (_Float16*)sh;               // [16][1024], XOR-swizzled, 32 KB
    _Float16* Vt    = (_Float16*)(sh + 32768);     // 8 KB (phase 2)
    u16*      mb2   = (u16*)(sh + 32768);          // 2 KB (phase 1, aliased)
    float*    redM  = (float*)(sh + 32768 + 2048);
    float*    redS  = (float*)(sh + 32768 + 2048 + 256);

    const int t = threadIdx.x;
    const int lane = t & 63;
    const int w = t >> 6;           // wave 0..3
    const int g = lane >> 4;        // 0..3
    const int n = lane & 15;
    const int bh = blockIdx.y;
    const int b = bh >> 4;
    const int qt = blockIdx.x;
    const int qtile = qt * 16;
    const int kbase = w * 256;
    const int qrow = qtile + g * 4;

    const float* Qb = Q + (size_t)bh * Sc * Dc;

    // ---- stage mask bits to mb2 [1024] u16 ----
    if constexpr (PRE) {
        if (t < 128) {
            const uint4 v = ((const uint4*)(MB + (size_t)(b * 64 + qt) * 1024))[t];
            ((uint4*)mb2)[t] = v;
        }
    } else {
        u16 m0 = 0, m1 = 0, m2 = 0, m3 = 0;
        const int* mp = M + ((size_t)b * Sc + qtile) * Sc + t * 4;
#pragma unroll
        for (int r = 0; r < 16; ++r) {
            const int4 mi = *(const int4*)(mp + (size_t)r * Sc);
            m0 |= (u16)((mi.x != 0 ? 1 : 0) << r);
            m1 |= (u16)((mi.y != 0 ? 1 : 0) << r);
            m2 |= (u16)((mi.z != 0 ? 1 : 0) << r);
            m3 |= (u16)((mi.w != 0 ? 1 : 0) << r);
        }
        u16x4 pk = {m0, m1, m2, m3};
        *(u16x4*)&mb2[t * 4] = pk;
    }

    // ---- Q A-fragments from global f32 (once per thread) ----
    half8 qf0, qf1;
    {
        const float* qr = Qb + (size_t)(qtile + n) * Dc;
        const float4 a0 = *(const float4*)&qr[g * 8];
        const float4 a1 = *(const float4*)&qr[g * 8 + 4];
        const float4 a2 = *(const float4*)&qr[32 + g * 8];
        const float4 a3 = *(const float4*)&qr[32 + g * 8 + 4];
        qf0 = cvt8(a0, a1);
        qf1 = cvt8(a2, a3);
    }
    __syncthreads();   // mb2 ready

    // ---- Phase 1: scores, 16 q-rows x wave's 256 keys ----
    float s[64];       // statically indexed only
#pragma unroll
    for (int kt = 0; kt < 16; ++kt) {
        const int key = kbase + kt * 16 + n;
        half8 kf0, kf1;
        if constexpr (PRE) {
            const _Float16* krh = Kh + ((size_t)bh * Sc + key) * Dc;
            kf0 = *(const half8*)&krh[g * 8];
            kf1 = *(const half8*)&krh[32 + g * 8];
        } else {
            const float* kr = K + ((size_t)bh * Sc + key) * Dc;
            const float4 b0 = *(const float4*)&kr[g * 8];
            const float4 b1 = *(const float4*)&kr[g * 8 + 4];
            const float4 b2 = *(const float4*)&kr[32 + g * 8];
            const float4 b3 = *(const float4*)&kr[32 + g * 8 + 4];
            kf0 = cvt8(b0, b1);
            kf1 = cvt8(b2, b3);
        }
        floatx4 acc = {0.f, 0.f, 0.f, 0.f};
        acc = __builtin_amdgcn_mfma_f32_16x16x32_f16(qf0, kf0, acc, 0, 0, 0);
        acc = __builtin_amdgcn_mfma_f32_16x16x32_f16(qf1, kf1, acc, 0, 0, 0);
        const unsigned mbits = mb2[kbase + kt * 16 + n];
#pragma unroll
        for (int r = 0; r < 4; ++r) {
            s[kt * 4 + r] = ((mbits >> (g * 4 + r)) & 1) ? acc[r] * SCALE : NEGV;
        }
    }

    // ---- Softmax ----
    float mx[4];
#pragma unroll
    for (int r = 0; r < 4; ++r) {
        float m = s[r];
#pragma unroll
        for (int kt = 1; kt < 16; ++kt) m = fmaxf(m, s[kt * 4 + r]);
        m = fmaxf(m, __shfl_xor(m, 1, 64));
        m = fmaxf(m, __shfl_xor(m, 2, 64));
        m = fmaxf(m, __shfl_xor(m, 4, 64));
        m = fmaxf(m, __shfl_xor(m, 8, 64));
        mx[r] = m;
    }
    if (n == 0) {
#pragma unroll
        for (int r = 0; r < 4; ++r) redM[w * 16 + g * 4 + r] = mx[r];
    }
    __syncthreads();
#pragma unroll
    for (int r = 0; r < 4; ++r) {
        mx[r] = fmaxf(fmaxf(redM[0 * 16 + g * 4 + r], redM[1 * 16 + g * 4 + r]),
                      fmaxf(redM[2 * 16 + g * 4 + r], redM[3 * 16 + g * 4 + r]));
    }
    float sum[4] = {0.f, 0.f, 0.f, 0.f};
#pragma unroll
    for (int kt = 0; kt < 16; ++kt) {
#pragma unroll
        for (int r = 0; r < 4; ++r) {
            const float p = __expf(s[kt * 4 + r] - mx[r]);
            s[kt * 4 + r] = p;
            sum[r] += p;
        }
    }
#pragma unroll
    for (int r = 0; r < 4; ++r) {
        float z = sum[r];
        z += __shfl_xor(z, 1, 64);
        z += __shfl_xor(z, 2, 64);
        z += __shfl_xor(z, 4, 64);
        z += __shfl_xor(z, 8, 64);
        sum[r] = z;
    }
    if (n == 0) {
#pragma unroll
        for (int r = 0; r < 4; ++r) redS[w * 16 + g * 4 + r] = sum[r];
    }
    __syncthreads();
    float inv[4];
#pragma unroll
    for (int r = 0; r < 4; ++r) {
        inv[r] = 1.0f / (redS[0 * 16 + g * 4 + r] + redS[1 * 16 + g * 4 + r] +
                         redS[2 * 16 + g * 4 + r] + redS[3 * 16 + g * 4 + r]);
    }

    // ---- P -> p_lds fp16, XOR-swizzled: elem (row,col) at [row][col ^ ((row&7)<<3)] ----
#pragma unroll
    for (int kt = 0; kt < 16; ++kt) {
        const int col = kbase + kt * 16 + n;
#pragma unroll
        for (int r = 0; r < 4; ++r) {
            const int row = g * 4 + r;
            p_lds[row * 1024 + (col ^ ((row & 7) << 3))] =
                (_Float16)(s[kt * 4 + r] * inv[r]);
        }
    }
    __syncthreads();

    // ---- Prefetch V chunk 0 (64 keys) into regs ----
    const int k_l = t >> 2;            // 0..63
    const int d8a = t & 3, d8b = (t & 3) + 4;
    half8 va8, vb8s;
    if constexpr (PRE) {
        const _Float16* vr = Vh + ((size_t)bh * Sc + k_l) * Dc;
        va8  = *(const half8*)&vr[d8a * 8];
        vb8s = *(const half8*)&vr[d8b * 8];
    } else {
        const float* vr = V + ((size_t)bh * Sc + k_l) * Dc;
        va8  = cvt8(*(const float4*)&vr[d8a * 8], *(const float4*)&vr[d8a * 8 + 4]);
        vb8s = cvt8(*(const float4*)&vr[d8b * 8], *(const float4*)&vr[d8b * 8 + 4]);
    }

    // ---- Attn store: b128 LDS readback -> coalesced float4 stores ----
    {
        const int row = t >> 4;
        float* arow = Attn + (size_t)bh * Sc * Sc + (size_t)(qtile + row) * Sc;
#pragma unroll
        for (int cc = 0; cc < 8; ++cc) {
            const int col = cc * 128 + (t & 15) * 8;
            const half8 h = *(const half8*)&p_lds[row * 1024 + (col ^ ((row & 7) << 3))];
            float4 f0, f1;
            f0.x = (float)h[0]; f0.y = (float)h[1]; f0.z = (float)h[2]; f0.w = (float)h[3];
            f1.x = (float)h[4]; f1.y = (float)h[5]; f1.z = (float)h[6]; f1.w = (float)h[7];
            *(float4*)&arow[col] = f0;
            *(float4*)&arow[col + 4] = f1;
        }
    }

    // Vt dest index (fp16 units) for (k_l, d8), contiguous over the half8:
    // (((k_l>>5)*4 + (d8>>1))*8 + ((k_l>>2)&1)*4 + ((k_l>>3)&3))*64 + (k_l&3)*16 + (d8&1)*8
    const int ia = (((k_l >> 5) * 4 + (d8a >> 1)) * 8 + ((k_l >> 2) & 1) * 4 + ((k_l >> 3) & 3)) * 64
                   + (k_l & 3) * 16 + (d8a & 1) * 8;
    const int ib = (((k_l >> 5) * 4 + (d8b >> 1)) * 8 + ((k_l >> 2) & 1) * 4 + ((k_l >> 3) & 3)) * 64
                   + (k_l & 3) * 16 + (d8b & 1) * 8;

    // ---- Phase 2: O = P @ V, 16 chunks of 64 keys, tr_read B-fragments ----
    floatx4 oacc = {0.f, 0.f, 0.f, 0.f};
    const unsigned vt_base = (unsigned)(uintptr_t)Vt;
    for (int c = 0; c < 16; ++c) {
        __syncthreads();                 // chunk c-1 consumers done
        *(half8*)&Vt[ia] = va8;
        *(half8*)&Vt[ib] = vb8s;
        __syncthreads();
        if (c < 15) {
            if constexpr (PRE) {
                const _Float16* vr = Vh + ((size_t)bh * Sc + (c + 1) * 64 + k_l) * Dc;
                va8  = *(const half8*)&vr[d8a * 8];
                vb8s = *(const half8*)&vr[d8b * 8];
            } else {
                const float* vr = V + ((size_t)bh * Sc + (c + 1) * 64 + k_l) * Dc;
                va8  = cvt8(*(const float4*)&vr[d8a * 8], *(const float4*)&vr[d8a * 8 + 4]);
                vb8s = cvt8(*(const float4*)&vr[d8b * 8], *(const float4*)&vr[d8b * 8 + 4]);
            }
        }
#pragma unroll
        for (int kb = 0; kb < 2; ++kb) {
            const int pcol = c * 64 + kb * 32 + g * 8;
            const half8 pa = *(const half8*)&p_lds[n * 1024 + (pcol ^ ((n & 7) << 3))];
            const unsigned vaddr = vt_base +
                ((((unsigned)kb * 4 + (unsigned)w) * 8 + (unsigned)g) * 64 + (unsigned)n * 4) * 2;
            half4v r0, r1;
            asm volatile("ds_read_b64_tr_b16 %0, %2\n\t"
                         "ds_read_b64_tr_b16 %1, %2 offset:512"
                         : "=&v"(r0), "=&v"(r1) : "v"(vaddr));
            asm volatile("s_waitcnt lgkmcnt(0)" ::: "memory");
            __builtin_amdgcn_sched_barrier(0);
            half8 vf;
            vf[0] = r0[0]; vf[1] = r0[1]; vf[2] = r0[2]; vf[3] = r0[3];
            vf[4] = r1[0]; vf[5] = r1[1]; vf[6] = r1[2]; vf[7] = r1[3];
            oacc = __builtin_amdgcn_mfma_f32_16x16x32_f16(pa, vf, oacc, 0, 0, 0);
        }
    }

    const int dcol = w * 16 + n;
    float* Ob = Out + (size_t)bh * Sc * Dc;
#pragma unroll
    for (int r = 0; r < 4; ++r) {
        Ob[(size_t)(qrow + r) * Dc + dcol] = oacc[r];
    }
}

extern "C" void kernel_launch(void* const* d_in, const int* in_sizes, int n_in,
                              void* d_out, int out_size, void* d_ws, size_t ws_size,
                              hipStream_t stream) {
    const float* Q = (const float*)d_in[0];
    const float* K = (const float*)d_in[1];
    const float* V = (const float*)d_in[2];
    const int*   M = (const int*)d_in[3];

    float* Out  = (float*)d_out;
    float* Attn = (float*)d_out + (size_t)Bc * Hc * Sc * Dc;

    const size_t nEl = (size_t)Bc * Hc * Sc * Dc;            // 8388608
    const size_t needed = nEl * 2 * 2 + (size_t)Bc * 64 * 1024 * 2;  // Kh+Vh+MB = 34 MB

    dim3 grid(Sc / 16, Bc * Hc);
    dim3 block(256);

    if (ws_size >= needed) {
        _Float16* Kh = (_Float16*)d_ws;
        _Float16* Vh = Kh + nEl;
        u16*      MB = (u16*)(Vh + nEl);
        cvt_f16_kernel<<<2048, 256, 0, stream>>>(K, V, Kh, Vh);
        pack_mask_kernel<<<2048, 256, 0, stream>>>(M, MB);
        attn4<true><<<grid, block, 0, stream>>>(Q, K, V, M, Kh, Vh, MB, Out, Attn);
    } else {
        attn4<false><<<grid, block, 0, stream>>>(Q, K, V, M, nullptr, nullptr, nullptr, Out, Attn);
    }
}

// Round 5
// 317.323 us; speedup vs baseline: 145.5234x; 1.0779x over previous
//
#include <hip/hip_runtime.h>
#include <stdint.h>

// B=8,H=16,S=1024,D=64 fp32 attention with full attention-matrix output.
// Outputs: out [B,H,S,D] then attention [B,H,S,S], concatenated fp32.

typedef _Float16 half8 __attribute__((ext_vector_type(8)));
typedef _Float16 half4v __attribute__((ext_vector_type(4)));
typedef float floatx4 __attribute__((ext_vector_type(4)));
typedef unsigned short u16;

constexpr int Bc = 8, Hc = 16, Sc = 1024, Dc = 64;
constexpr float NEGV = -1000000000.0f;
constexpr float SCALE = 0.125f;   // 1/sqrt(64), folded into Q fragments
constexpr int MPITCH = 72;        // mb2 row pitch in u16 (bank-staggers rows)

__device__ inline half8 cvt8(float4 a, float4 b) {
    half8 h;
    h[0] = (_Float16)a.x; h[1] = (_Float16)a.y; h[2] = (_Float16)a.z; h[3] = (_Float16)a.w;
    h[4] = (_Float16)b.x; h[5] = (_Float16)b.y; h[6] = (_Float16)b.z; h[7] = (_Float16)b.w;
    return h;
}

// ---- pre-kernel 1: K,V fp32 -> fp16 ----
__global__ __launch_bounds__(256) void cvt_f16_kernel(
    const float* __restrict__ K, const float* __restrict__ V,
    _Float16* __restrict__ Kh, _Float16* __restrict__ Vh)
{
    const size_t nv = (size_t)Bc * Hc * Sc * Dc / 4;
    for (size_t i = (size_t)blockIdx.x * blockDim.x + threadIdx.x; i < 2 * nv;
         i += (size_t)gridDim.x * blockDim.x) {
        const bool isK = i < nv;
        const size_t j = isK ? i : i - nv;
        const float4 f = ((const float4*)(isK ? K : V))[j];
        half4v h;
        h[0] = (_Float16)f.x; h[1] = (_Float16)f.y;
        h[2] = (_Float16)f.z; h[3] = (_Float16)f.w;
        *(half4v*)((isK ? Kh : Vh) + j * 4) = h;
    }
}

// ---- pre-kernel 2: mask -> row-major u16 bitmask: MB[(b*64+qt)*1024 + row*64 + kc]
// bit j of MB[..] = mask[b][qt*16+row][kc*16+j]
__global__ __launch_bounds__(256) void pack_mask_kernel(
    const int* __restrict__ M, u16* __restrict__ MB)
{
    const int id = blockIdx.x;          // 512 = 8b * 64qt
    const int qt = id & 63, b = id >> 6;
    const int t = threadIdx.x;
#pragma unroll
    for (int iter = 0; iter < 4; ++iter) {
        const int row = iter * 4 + (t >> 6);
        const int kc = t & 63;
        const int* mp = M + ((size_t)b * Sc + qt * 16 + row) * Sc + kc * 16;
        unsigned m = 0;
#pragma unroll
        for (int j4 = 0; j4 < 4; ++j4) {
            const int4 mi = *(const int4*)(mp + j4 * 4);
            m |= (mi.x != 0 ? 1u : 0u) << (j4 * 4 + 0);
            m |= (mi.y != 0 ? 1u : 0u) << (j4 * 4 + 1);
            m |= (mi.z != 0 ? 1u : 0u) << (j4 * 4 + 2);
            m |= (mi.w != 0 ? 1u : 0u) << (j4 * 4 + 3);
        }
        MB[(size_t)(b * 64 + qt) * 1024 + row * 64 + kc] = (u16)m;
    }
}

template<bool PRE>
__global__ __launch_bounds__(256, 4) void attn5(
    const float* __restrict__ Q, const float* __restrict__ K,
    const float* __restrict__ V, const int* __restrict__ M,
    const _Float16* __restrict__ Kh, const _Float16* __restrict__ Vh,
    const u16* __restrict__ MB,
    float* __restrict__ Out, float* __restrict__ Attn)
{
    // 40960 B exactly -> 4 blocks/CU. mb2 + red alias the Vt region (dead in phase 2 / phase 1 resp.)
    __shared__ __align__(16) unsigned char sh[40960];
    _Float16* p_lds = (_Float16*)sh;               // [16][1024] XOR-swizzled, 32 KB
    _Float16* Vt    = (_Float16*)(sh + 32768);     // 8 KB (phase 2 only)
    u16*      mb2   = (u16*)(sh + 32768);          // [16][MPITCH] (phase 1 only)
    float*    redM  = (float*)(sh + 36864);        // 64 floats (softmax only)
    float*    redS  = (float*)(sh + 37120);        // 64 floats

    const int t = threadIdx.x;
    const int lane = t & 63;
    const int w = t >> 6;           // wave 0..3
    const int g = lane >> 4;        // 0..3
    const int n = lane & 15;
    const int bh = blockIdx.y;
    const int b = bh >> 4;
    const int qt = blockIdx.x;
    const int qtile = qt * 16;
    const int kbase = w * 256;      // wave's key slice for phase 1

    // ---- stage mask bits -> mb2 [16][MPITCH] u16 (u16 kc covers keys kc*16..+15) ----
    if constexpr (PRE) {
        if (t < 128) {
            const uint4 v = ((const uint4*)(MB + (size_t)(b * 64 + qt) * 1024))[t];
            const int row = t >> 3, kc = (t & 7) * 8;
            *(uint4*)&mb2[row * MPITCH + kc] = v;
        }
    } else {
#pragma unroll
        for (int iter = 0; iter < 4; ++iter) {
            const int row = iter * 4 + (t >> 6), kc = t & 63;
            const int* mp = M + ((size_t)b * Sc + qtile + row) * Sc + kc * 16;
            unsigned m = 0;
#pragma unroll
            for (int j4 = 0; j4 < 4; ++j4) {
                const int4 mi = *(const int4*)(mp + j4 * 4);
                m |= (mi.x != 0 ? 1u : 0u) << (j4 * 4 + 0);
                m |= (mi.y != 0 ? 1u : 0u) << (j4 * 4 + 1);
                m |= (mi.z != 0 ? 1u : 0u) << (j4 * 4 + 2);
                m |= (mi.w != 0 ? 1u : 0u) << (j4 * 4 + 3);
            }
            mb2[row * MPITCH + kc] = (u16)m;
        }
    }

    // ---- Q B-fragments from global f32, pre-scaled by 1/sqrt(dk) ----
    half8 qf0, qf1;
    {
        const float* qr = Q + ((size_t)bh * Sc + qtile + n) * Dc;
        float4 a0 = *(const float4*)&qr[g * 8];
        float4 a1 = *(const float4*)&qr[g * 8 + 4];
        float4 a2 = *(const float4*)&qr[32 + g * 8];
        float4 a3 = *(const float4*)&qr[32 + g * 8 + 4];
        a0.x *= SCALE; a0.y *= SCALE; a0.z *= SCALE; a0.w *= SCALE;
        a1.x *= SCALE; a1.y *= SCALE; a1.z *= SCALE; a1.w *= SCALE;
        a2.x *= SCALE; a2.y *= SCALE; a2.z *= SCALE; a2.w *= SCALE;
        a3.x *= SCALE; a3.y *= SCALE; a3.z *= SCALE; a3.w *= SCALE;
        qf0 = cvt8(a0, a1);
        qf1 = cvt8(a2, a3);
    }
    __syncthreads();   // mb2 ready

    // ---- per-thread mask preload: 16 u16 for (q-row n, this wave's 16 key-chunks) ----
    union { uint4 v[2]; u16 h[16]; } mu;
    mu.v[0] = *(const uint4*)&mb2[n * MPITCH + w * 16];
    mu.v[1] = *(const uint4*)&mb2[n * MPITCH + w * 16 + 8];

    // ---- Phase 1 (swapped): C[key][q] = K . Q^T. Thread owns q-row n,
    //      keys kbase + kt*16 + g*4 + r  (4 CONTIGUOUS keys per kt) ----
    float s[64];   // statically indexed only
#pragma unroll
    for (int kt = 0; kt < 16; ++kt) {
        const int key = kbase + kt * 16 + n;
        half8 kf0, kf1;
        if constexpr (PRE) {
            const _Float16* krh = Kh + ((size_t)bh * Sc + key) * Dc;
            kf0 = *(const half8*)&krh[g * 8];
            kf1 = *(const half8*)&krh[32 + g * 8];
        } else {
            const float* kr = K + ((size_t)bh * Sc + key) * Dc;
            kf0 = cvt8(*(const float4*)&kr[g * 8], *(const float4*)&kr[g * 8 + 4]);
            kf1 = cvt8(*(const float4*)&kr[32 + g * 8], *(const float4*)&kr[32 + g * 8 + 4]);
        }
        floatx4 acc = {0.f, 0.f, 0.f, 0.f};
        acc = __builtin_amdgcn_mfma_f32_16x16x32_f16(kf0, qf0, acc, 0, 0, 0);
        acc = __builtin_amdgcn_mfma_f32_16x16x32_f16(kf1, qf1, acc, 0, 0, 0);
        const unsigned mbits = mu.h[kt];
#pragma unroll
        for (int r = 0; r < 4; ++r) {
            s[kt * 4 + r] = ((mbits >> (g * 4 + r)) & 1) ? acc[r] : NEGV;
        }
    }

    // ---- Softmax over row n (thread-local 64 -> g-lanes -> waves) ----
    float mloc = -3.4e38f;
#pragma unroll
    for (int kt = 0; kt < 16; ++kt) {
        mloc = fmaxf(mloc, fmaxf(fmaxf(s[kt * 4], s[kt * 4 + 1]),
                                 fmaxf(s[kt * 4 + 2], s[kt * 4 + 3])));
    }
    mloc = fmaxf(mloc, __shfl_xor(mloc, 16, 64));
    mloc = fmaxf(mloc, __shfl_xor(mloc, 32, 64));
    if (lane < 16) redM[w * 16 + n] = mloc;
    __syncthreads();
    const float mx = fmaxf(fmaxf(redM[n], redM[16 + n]),
                           fmaxf(redM[32 + n], redM[48 + n]));
    float sloc = 0.f;
#pragma unroll
    for (int kt = 0; kt < 16; ++kt) {
#pragma unroll
        for (int r = 0; r < 4; ++r) {
            const float p = __expf(s[kt * 4 + r] - mx);
            s[kt * 4 + r] = p;
            sloc += p;
        }
    }
    sloc += __shfl_xor(sloc, 16, 64);
    sloc += __shfl_xor(sloc, 32, 64);
    if (lane < 16) redS[w * 16 + n] = sloc;
    __syncthreads();
    const float inv = __builtin_amdgcn_rcpf(redS[n] + redS[16 + n] +
                                            redS[32 + n] + redS[48 + n]);

    // ---- P -> p_lds (row n), b64 writes of 4 contiguous keys, XOR-swizzled ----
    const unsigned swzn = (unsigned)((n & 7) << 3);
#pragma unroll
    for (int kt = 0; kt < 16; ++kt) {
        const int col = kbase + kt * 16 + g * 4;
        half4v hp;
        hp[0] = (_Float16)(s[kt * 4 + 0] * inv);
        hp[1] = (_Float16)(s[kt * 4 + 1] * inv);
        hp[2] = (_Float16)(s[kt * 4 + 2] * inv);
        hp[3] = (_Float16)(s[kt * 4 + 3] * inv);
        *(half4v*)&p_lds[n * 1024 + (col ^ swzn)] = hp;
    }
    __syncthreads();   // p_lds ready; mb2/red dead -> Vt region free

    // ---- Prefetch V chunk 0 (64 keys) into regs ----
    const int k_l = t >> 2;
    const int d8a = t & 3, d8b = (t & 3) + 4;
    half8 va8, vb8s;
    if constexpr (PRE) {
        const _Float16* vr = Vh + ((size_t)bh * Sc + k_l) * Dc;
        va8  = *(const half8*)&vr[d8a * 8];
        vb8s = *(const half8*)&vr[d8b * 8];
    } else {
        const float* vr = V + ((size_t)bh * Sc + k_l) * Dc;
        va8  = cvt8(*(const float4*)&vr[d8a * 8], *(const float4*)&vr[d8a * 8 + 4]);
        vb8s = cvt8(*(const float4*)&vr[d8b * 8], *(const float4*)&vr[d8b * 8 + 4]);
    }

    // Vt dest indices (fp16 units), tr-read subtiled layout (same as r4)
    const int ia = (((k_l >> 5) * 4 + (d8a >> 1)) * 8 + ((k_l >> 2) & 1) * 4 + ((k_l >> 3) & 3)) * 64
                   + (k_l & 3) * 16 + (d8a & 1) * 8;
    const int ib = (((k_l >> 5) * 4 + (d8b >> 1)) * 8 + ((k_l >> 2) & 1) * 4 + ((k_l >> 3) & 3)) * 64
                   + (k_l & 3) * 16 + (d8b & 1) * 8;

    // ---- Phase 2: PV chunks with interleaved Attn stores ----
    const int row_a = t >> 4, ca = (t & 15) * 4;
    const unsigned swza = (unsigned)((row_a & 7) << 3);
    float* arow = Attn + (size_t)bh * Sc * Sc + (size_t)(qtile + row_a) * Sc;

    floatx4 oacc = {0.f, 0.f, 0.f, 0.f};
    const unsigned vt_base = (unsigned)(uintptr_t)Vt;
    for (int c = 0; c < 16; ++c) {
        __syncthreads();               // chunk c-1 consumers done
        *(half8*)&Vt[ia] = va8;
        *(half8*)&Vt[ib] = vb8s;
        __syncthreads();
        if (c < 15) {
            if constexpr (PRE) {
                const _Float16* vr = Vh + ((size_t)bh * Sc + (c + 1) * 64 + k_l) * Dc;
                va8  = *(const half8*)&vr[d8a * 8];
                vb8s = *(const half8*)&vr[d8b * 8];
            } else {
                const float* vr = V + ((size_t)bh * Sc + (c + 1) * 64 + k_l) * Dc;
                va8  = cvt8(*(const float4*)&vr[d8a * 8], *(const float4*)&vr[d8a * 8 + 4]);
                vb8s = cvt8(*(const float4*)&vr[d8b * 8], *(const float4*)&vr[d8b * 8 + 4]);
            }
        }
        // Attn store for this 64-col chunk (hides under barriers/MFMA)
        {
            const int col = c * 64 + ca;
            const half4v h = *(const half4v*)&p_lds[row_a * 1024 + (col ^ swza)];
            float4 f;
            f.x = (float)h[0]; f.y = (float)h[1]; f.z = (float)h[2]; f.w = (float)h[3];
            *(float4*)&arow[col] = f;
        }
        __builtin_amdgcn_s_setprio(1);
#pragma unroll
        for (int kb = 0; kb < 2; ++kb) {
            const int pcol = c * 64 + kb * 32 + g * 8;
            const half8 pa = *(const half8*)&p_lds[n * 1024 + (pcol ^ swzn)];
            const unsigned vaddr = vt_base +
                ((((unsigned)kb * 4 + (unsigned)w) * 8 + (unsigned)g) * 64 + (unsigned)n * 4) * 2;
            half4v r0, r1;
            asm volatile("ds_read_b64_tr_b16 %0, %2\n\t"
                         "ds_read_b64_tr_b16 %1, %2 offset:512"
                         : "=&v"(r0), "=&v"(r1) : "v"(vaddr));
            asm volatile("s_waitcnt lgkmcnt(0)" ::: "memory");
            __builtin_amdgcn_sched_barrier(0);
            half8 vf;
            vf[0] = r0[0]; vf[1] = r0[1]; vf[2] = r0[2]; vf[3] = r0[3];
            vf[4] = r1[0]; vf[5] = r1[1]; vf[6] = r1[2]; vf[7] = r1[3];
            oacc = __builtin_amdgcn_mfma_f32_16x16x32_f16(pa, vf, oacc, 0, 0, 0);
        }
        __builtin_amdgcn_s_setprio(0);
    }

    const int dcol = w * 16 + n;
    const int qrow = qtile + g * 4;
    float* Ob = Out + (size_t)bh * Sc * Dc;
#pragma unroll
    for (int r = 0; r < 4; ++r) {
        Ob[(size_t)(qrow + r) * Dc + dcol] = oacc[r];
    }
}

extern "C" void kernel_launch(void* const* d_in, const int* in_sizes, int n_in,
                              void* d_out, int out_size, void* d_ws, size_t ws_size,
                              hipStream_t stream) {
    const float* Q = (const float*)d_in[0];
    const float* K = (const float*)d_in[1];
    const float* V = (const float*)d_in[2];
    const int*   M = (const int*)d_in[3];

    float* Out  = (float*)d_out;
    float* Attn = (float*)d_out + (size_t)Bc * Hc * Sc * Dc;

    const size_t nEl = (size_t)Bc * Hc * Sc * Dc;
    const size_t needed = nEl * 2 * 2 + (size_t)Bc * 64 * 1024 * 2;

    dim3 grid(Sc / 16, Bc * Hc);
    dim3 block(256);

    if (ws_size >= needed) {
        _Float16* Kh = (_Float16*)d_ws;
        _Float16* Vh = Kh + nEl;
        u16*      MB = (u16*)(Vh + nEl);
        cvt_f16_kernel<<<2048, 256, 0, stream>>>(K, V, Kh, Vh);
        pack_mask_kernel<<<512, 256, 0, stream>>>(M, MB);
        attn5<true><<<grid, block, 0, stream>>>(Q, K, V, M, Kh, Vh, MB, Out, Attn);
    } else {
        attn5<false><<<grid, block, 0, stream>>>(Q, K, V, M, nullptr, nullptr, nullptr, Out, Attn);
    }
}